// Round 1
// baseline (1031.214 us; speedup 1.0000x reference)
//
#include <hip/hip_runtime.h>

#define H   256
#define NCC 5
#define NBN 160
#define TVV 2048
#define TQQ 128

__device__ __forceinline__ float tanh_fast(float x) {
  // tanh via hardware exp; rel err ~1e-6, clamp avoids inf/inf
  x = fminf(fmaxf(x, -15.f), 15.f);
  float e = __expf(2.f * x);
  return (e - 1.f) / (e + 1.f);
}

// ---------------------------------------------------------------------------
// K0: per-bn GEMVs: Uhv = hh@Uav + bav, Uht = hh@Uat + bat, Wbs = hh@Wb,
//     Hwh = hh@Whh + bh; plus per-bn masked lengths.
// ---------------------------------------------------------------------------
__global__ __launch_bounds__(256) void k_prep(
    const float* __restrict__ h,
    const float* __restrict__ Uav, const float* __restrict__ Uat,
    const float* __restrict__ Wb,  const float* __restrict__ Whh,
    const float* __restrict__ bav, const float* __restrict__ bat,
    const float* __restrict__ bh,
    const int* __restrict__ video_lens, const int* __restrict__ qa_lens,
    float* __restrict__ Uhv, float* __restrict__ Uht,
    float* __restrict__ WbsA, float* __restrict__ HwhA,
    int* __restrict__ lenv, int* __restrict__ lent)
{
  const int bn = blockIdx.x, tid = threadIdx.x;
  __shared__ float hs[H];
  hs[tid] = h[bn * H + tid];
  __syncthreads();
  float a0 = bav[tid], a1 = bat[tid], a2 = 0.f, a3 = bh[tid];
#pragma unroll 4
  for (int k = 0; k < H; ++k) {
    const float x = hs[k];
    a0 = fmaf(x, Uav[k * H + tid], a0);
    a1 = fmaf(x, Uat[k * H + tid], a1);
    a2 = fmaf(x, Wb [k * H + tid], a2);
    a3 = fmaf(x, Whh[k * H + tid], a3);
  }
  Uhv [bn * H + tid] = a0;
  Uht [bn * H + tid] = a1;
  WbsA[bn * H + tid] = a2;
  HwhA[bn * H + tid] = a3;
  if (tid == 0) {
    const int b = bn / NCC;
    lenv[bn] = video_lens[b];
    int m = qa_lens[b * NCC];
    for (int j = 1; j < NCC; ++j) {
      int q = qa_lens[b * NCC + j];
      m = (q > m) ? q : m;
    }
    lent[bn] = m;
  }
}

// ---------------------------------------------------------------------------
// K1: ev[bn][t] = sum_h tanh( sum_k X[bn,t,k]*W[k,h] + U[bn,h] ) * Vv[h]
// Register-tiled fp32 GEMM with fused epilogue.
// Block: 256 threads -> 64 frames x 256 h. Thread: 8 frames x 8 h.
// K staged in chunks of 32: Ws[32][256] (32KB) + transposed A tile.
// ---------------------------------------------------------------------------
__global__ __launch_bounds__(256) void k_logits(
    const float* __restrict__ X,    // [NBN, T, H]
    const float* __restrict__ W,    // [H, H]  (W[k][h])
    const float* __restrict__ U,    // [NBN, H] (bias already folded)
    const float* __restrict__ Vv,   // [H]
    const int*  __restrict__ lenp,  // [NBN]
    int T,
    float* __restrict__ EV)         // [NBN, T]
{
  const int bn = blockIdx.y;
  const int t0 = blockIdx.x * 64;
  const int len = lenp[bn];
  if (t0 >= len) return;           // fully-masked block: skip

  const int tid = threadIdx.x;
  const int hg = tid & 31;         // h octet: h = hg*8 .. hg*8+7
  const int tg = tid >> 5;         // frame octet: t = t0 + tg*8 .. +7

  __shared__ float Ws[32][H];      // 32 KB
  __shared__ float AsT[32][72];    // transposed A chunk, 72-float stride (16B aligned rows)

  float acc[8][8];
#pragma unroll
  for (int i = 0; i < 8; ++i)
#pragma unroll
    for (int j = 0; j < 8; ++j) acc[i][j] = 0.f;

  const float* Xrow = X + ((size_t)bn * T + t0) * H;

  for (int k0 = 0; k0 < H; k0 += 32) {
    __syncthreads();  // protect LDS from previous chunk's readers
    // stage W chunk: rows k0..k0+31, all 256 cols (float4, coalesced)
    {
      const int r = tid >> 6;            // 0..3
      const int c = (tid & 63) * 4;      // 0..252
#pragma unroll
      for (int i = 0; i < 8; ++i) {
        const float4 w = *(const float4*)&W[(size_t)(k0 + r + i * 4) * H + c];
        *(float4*)&Ws[r + i * 4][c] = w;
      }
    }
    // stage A chunk transposed: AsT[k][t]  (64 frames x 32 k)
    {
      const int ti = tid >> 2;           // 0..63
      const int kq = (tid & 3) * 8;      // 0,8,16,24
      const float4 v0 = *(const float4*)&Xrow[(size_t)ti * H + k0 + kq];
      const float4 v1 = *(const float4*)&Xrow[(size_t)ti * H + k0 + kq + 4];
      AsT[kq + 0][ti] = v0.x; AsT[kq + 1][ti] = v0.y;
      AsT[kq + 2][ti] = v0.z; AsT[kq + 3][ti] = v0.w;
      AsT[kq + 4][ti] = v1.x; AsT[kq + 5][ti] = v1.y;
      AsT[kq + 6][ti] = v1.z; AsT[kq + 7][ti] = v1.w;
    }
    __syncthreads();
#pragma unroll 4
    for (int k = 0; k < 32; ++k) {
      const float4 a0 = *(const float4*)&AsT[k][tg * 8];
      const float4 a1 = *(const float4*)&AsT[k][tg * 8 + 4];
      const float4 b0 = *(const float4*)&Ws[k][hg * 8];
      const float4 b1 = *(const float4*)&Ws[k][hg * 8 + 4];
      const float av_[8] = {a0.x, a0.y, a0.z, a0.w, a1.x, a1.y, a1.z, a1.w};
      const float bv_[8] = {b0.x, b0.y, b0.z, b0.w, b1.x, b1.y, b1.z, b1.w};
#pragma unroll
      for (int i = 0; i < 8; ++i)
#pragma unroll
        for (int j = 0; j < 8; ++j)
          acc[i][j] = fmaf(av_[i], bv_[j], acc[i][j]);
    }
  }

  // epilogue: + U, tanh, * Vv, reduce over h (32 lanes share a frame octet)
  float u[8], vv[8];
#pragma unroll
  for (int j = 0; j < 8; ++j) {
    u[j]  = U[bn * H + hg * 8 + j];
    vv[j] = Vv[hg * 8 + j];
  }
#pragma unroll
  for (int i = 0; i < 8; ++i) {
    float p = 0.f;
#pragma unroll
    for (int j = 0; j < 8; ++j) p = fmaf(tanh_fast(acc[i][j] + u[j]), vv[j], p);
    p += __shfl_xor(p, 16);
    p += __shfl_xor(p, 8);
    p += __shfl_xor(p, 4);
    p += __shfl_xor(p, 2);
    p += __shfl_xor(p, 1);
    if (hg == 0) EV[(size_t)bn * T + t0 + tg * 8 + i] = p;
  }
}

// ---------------------------------------------------------------------------
// K2: masked softmax over ev[bn][0:len] + weighted sum over X rows
// ---------------------------------------------------------------------------
template <int T>
__global__ __launch_bounds__(256) void k_softmax_pv(
    const float* __restrict__ EV,
    const float* __restrict__ X,     // [NBN, T, H]
    const int*  __restrict__ lenp,
    float* __restrict__ OUT)         // [NBN, H]
{
  const int bn = blockIdx.x, tid = threadIdx.x;
  const int len = lenp[bn];
  __shared__ float pl[T];
  __shared__ float red[8];
  const float* ev = EV + (size_t)bn * T;

  float m = -1e30f;
  for (int t = tid; t < len; t += 256) m = fmaxf(m, ev[t]);
  for (int off = 32; off; off >>= 1) m = fmaxf(m, __shfl_xor(m, off));
  if ((tid & 63) == 0) red[tid >> 6] = m;
  __syncthreads();
  m = fmaxf(fmaxf(red[0], red[1]), fmaxf(red[2], red[3]));

  float s = 0.f;
  for (int t = tid; t < len; t += 256) {
    const float p = __expf(ev[t] - m);
    pl[t] = p;
    s += p;
  }
  for (int off = 32; off; off >>= 1) s += __shfl_xor(s, off);
  if ((tid & 63) == 0) red[4 + (tid >> 6)] = s;
  __syncthreads();
  s = red[4] + red[5] + red[6] + red[7];
  const float inv = 1.f / s;

  // PV: thread owns h = tid; 8-way unrolled for memory-level parallelism
  const float* Xb = X + (size_t)bn * T * H;
  float acc = 0.f;
  int t = 0;
  for (; t + 8 <= len; t += 8) {
#pragma unroll
    for (int j = 0; j < 8; ++j)
      acc = fmaf(pl[t + j], Xb[(size_t)(t + j) * H + tid], acc);
  }
  for (; t < len; ++t) acc = fmaf(pl[t], Xb[(size_t)t * H + tid], acc);
  OUT[bn * H + tid] = acc * inv;
}

// ---------------------------------------------------------------------------
// K3: final gating + output
// ---------------------------------------------------------------------------
__global__ __launch_bounds__(256) void k_final(
    const float* __restrict__ HVS, const float* __restrict__ HTS,
    const float* __restrict__ Wvs, const float* __restrict__ bvs,
    const float* __restrict__ Wqs, const float* __restrict__ bqs,
    const float* __restrict__ Vbv, const float* __restrict__ Vbt,
    const float* __restrict__ bbv, const float* __restrict__ bbt,
    const float* __restrict__ wb,
    const float* __restrict__ WbsA, const float* __restrict__ HwhA,
    float* __restrict__ out)
{
  const int bn = blockIdx.x, tid = threadIdx.x;
  __shared__ float hv[H], ht[H];
  __shared__ float red[8];
  hv[tid] = HVS[bn * H + tid];
  ht[tid] = HTS[bn * H + tid];
  __syncthreads();

  const float wbs = WbsA[bn * H + tid];
  float hv2 = bvs[tid], ht2 = bqs[tid];
  float mv = bbv[tid] + wbs, mt = bbt[tid] + wbs;
#pragma unroll 4
  for (int k = 0; k < H; ++k) {
    const float a = hv[k], c = ht[k];
    hv2 = fmaf(a, Wvs[k * H + tid], hv2);
    ht2 = fmaf(c, Wqs[k * H + tid], ht2);
    mv  = fmaf(a, Vbv[k * H + tid], mv);
    mt  = fmaf(c, Vbt[k * H + tid], mt);
  }
  const float w = wb[tid];
  float sv = tanh_fast(mv) * w;
  float st = tanh_fast(mt) * w;
  for (int off = 32; off; off >>= 1) {
    sv += __shfl_xor(sv, off);
    st += __shfl_xor(st, off);
  }
  if ((tid & 63) == 0) { red[tid >> 6] = sv; red[4 + (tid >> 6)] = st; }
  __syncthreads();
  sv = red[0] + red[1] + red[2] + red[3];
  st = red[4] + red[5] + red[6] + red[7];
  const float mx = fmaxf(sv, st);
  const float e0 = __expf(sv - mx), e1 = __expf(st - mx);
  const float den = 1.f / (e0 + e1);
  out[bn * H + tid] = tanh_fast(HwhA[bn * H + tid] + (e0 * den) * hv2 + (e1 * den) * ht2);
}

// ---------------------------------------------------------------------------
extern "C" void kernel_launch(void* const* d_in, const int* in_sizes, int n_in,
                              void* d_out, int out_size, void* d_ws, size_t ws_size,
                              hipStream_t stream) {
  const float* h   = (const float*)d_in[0];
  const float* hf  = (const float*)d_in[1];
  const float* htx = (const float*)d_in[2];
  const float* Wav = (const float*)d_in[3];
  const float* Wat = (const float*)d_in[4];
  const float* Uav = (const float*)d_in[5];
  const float* Uat = (const float*)d_in[6];
  const float* Vav = (const float*)d_in[7];
  const float* Vat = (const float*)d_in[8];
  const float* bav = (const float*)d_in[9];
  const float* bat = (const float*)d_in[10];
  const float* Whh = (const float*)d_in[11];
  const float* bh  = (const float*)d_in[12];
  const float* Wvs = (const float*)d_in[13];
  const float* bvs = (const float*)d_in[14];
  const float* Wqs = (const float*)d_in[15];
  const float* bqs = (const float*)d_in[16];
  const float* Wb  = (const float*)d_in[17];
  const float* Vbv = (const float*)d_in[18];
  const float* Vbt = (const float*)d_in[19];
  const float* bbv = (const float*)d_in[20];
  const float* bbt = (const float*)d_in[21];
  const float* wb  = (const float*)d_in[22];
  const int* video_lens = (const int*)d_in[23];
  const int* qa_lens    = (const int*)d_in[24];

  float* ws   = (float*)d_ws;
  float* Uhv  = ws;                          // 160*256
  float* Uht  = Uhv  + NBN * H;
  float* WbsA = Uht  + NBN * H;
  float* HwhA = WbsA + NBN * H;
  float* HVS  = HwhA + NBN * H;
  float* HTS  = HVS  + NBN * H;
  float* EVb  = HTS  + NBN * H;              // 160*2048
  float* ETb  = EVb  + (size_t)NBN * TVV;    // 160*128
  int*   lenv = (int*)(ETb + (size_t)NBN * TQQ);
  int*   lent = lenv + NBN;

  k_prep<<<NBN, 256, 0, stream>>>(h, Uav, Uat, Wb, Whh, bav, bat, bh,
                                  video_lens, qa_lens, Uhv, Uht, WbsA, HwhA,
                                  lenv, lent);
  k_logits<<<dim3(TVV / 64, NBN), 256, 0, stream>>>(hf, Wav, Uhv, Vav, lenv, TVV, EVb);
  k_logits<<<dim3(TQQ / 64, NBN), 256, 0, stream>>>(htx, Wat, Uht, Vat, lent, TQQ, ETb);
  k_softmax_pv<TVV><<<NBN, 256, 0, stream>>>(EVb, hf, lenv, HVS);
  k_softmax_pv<TQQ><<<NBN, 256, 0, stream>>>(ETb, htx, lent, HTS);
  k_final<<<NBN, 256, 0, stream>>>(HVS, HTS, Wvs, bvs, Wqs, bqs, Vbv, Vbt,
                                   bbv, bbt, wb, WbsA, HwhA, (float*)d_out);
}

// Round 2
// 890.741 us; speedup vs baseline: 1.1577x; 1.1577x over previous
//
#include <hip/hip_runtime.h>

#define H   256
#define NCC 5
#define NBN 160
#define TVV 2048
#define TQQ 128

typedef short bf16x8 __attribute__((ext_vector_type(8)));
typedef float f32x4  __attribute__((ext_vector_type(4)));

__device__ __forceinline__ float tanh_fast(float x) {
  x = fminf(fmaxf(x, -15.f), 15.f);
  float e = __expf(2.f * x);
  return (e - 1.f) / (e + 1.f);
}

__device__ __forceinline__ short f2b(float f) {
  union { float f; unsigned u; } v; v.f = f;
  return (short)((v.u + 0x7fffu + ((v.u >> 16) & 1u)) >> 16);  // RNE
}

// ---------------------------------------------------------------------------
// K-1: W[k][h] fp32 -> Wt[h][k] bf16, for both attention weight matrices.
// ---------------------------------------------------------------------------
__global__ __launch_bounds__(256) void k_wt(
    const float* __restrict__ W0, const float* __restrict__ W1,
    short* __restrict__ T0, short* __restrict__ T1)
{
  const float* W = blockIdx.z ? W1 : W0;
  short* Wt = blockIdx.z ? T1 : T0;
  __shared__ float t[32][33];
  const int k0 = blockIdx.y * 32, h0 = blockIdx.x * 32;
  const int tx = threadIdx.x & 31, ty = threadIdx.x >> 5;  // ty: 0..7
#pragma unroll
  for (int i = 0; i < 4; ++i) {
    const int k = ty + i * 8;
    t[k][tx] = W[(size_t)(k0 + k) * H + h0 + tx];
  }
  __syncthreads();
#pragma unroll
  for (int i = 0; i < 4; ++i) {
    const int hh = ty + i * 8;
    Wt[(size_t)(h0 + hh) * H + k0 + tx] = f2b(t[tx][hh]);
  }
}

// ---------------------------------------------------------------------------
// K0: per-bn GEMVs + per-bn masked lengths.
// ---------------------------------------------------------------------------
__global__ __launch_bounds__(256) void k_prep(
    const float* __restrict__ h,
    const float* __restrict__ Uav, const float* __restrict__ Uat,
    const float* __restrict__ Wb,  const float* __restrict__ Whh,
    const float* __restrict__ bav, const float* __restrict__ bat,
    const float* __restrict__ bh,
    const int* __restrict__ video_lens, const int* __restrict__ qa_lens,
    float* __restrict__ Uhv, float* __restrict__ Uht,
    float* __restrict__ WbsA, float* __restrict__ HwhA,
    int* __restrict__ lenv, int* __restrict__ lent)
{
  const int bn = blockIdx.x, tid = threadIdx.x;
  __shared__ float hs[H];
  hs[tid] = h[bn * H + tid];
  __syncthreads();
  float a0 = bav[tid], a1 = bat[tid], a2 = 0.f, a3 = bh[tid];
#pragma unroll 4
  for (int k = 0; k < H; ++k) {
    const float x = hs[k];
    a0 = fmaf(x, Uav[k * H + tid], a0);
    a1 = fmaf(x, Uat[k * H + tid], a1);
    a2 = fmaf(x, Wb [k * H + tid], a2);
    a3 = fmaf(x, Whh[k * H + tid], a3);
  }
  Uhv [bn * H + tid] = a0;
  Uht [bn * H + tid] = a1;
  WbsA[bn * H + tid] = a2;
  HwhA[bn * H + tid] = a3;
  if (tid == 0) {
    const int b = bn / NCC;
    lenv[bn] = video_lens[b];
    int m = qa_lens[b * NCC];
    for (int j = 1; j < NCC; ++j) {
      int q = qa_lens[b * NCC + j];
      m = (q > m) ? q : m;
    }
    lent[bn] = m;
  }
}

// ---------------------------------------------------------------------------
// K1: ev[bn][t] = sum_h tanh( (X@W)[t,h] + U[h] ) * Vv[h]  via bf16 MFMA.
// 256 thr = 4 waves, 16 rows/wave, 64 rows/block. No LDS; fragments straight
// from global (X fp32 -> bf16 in-register; Wt bf16 is L1/L2-hot).
// ---------------------------------------------------------------------------
__global__ __launch_bounds__(256) void k_logits_mfma(
    const float* __restrict__ X,    // [NBN, T, H] fp32
    const short* __restrict__ Wt,   // [H][H] bf16, Wt[h][k]
    const float* __restrict__ U,    // [NBN, H] (bias folded)
    const float* __restrict__ Vv,   // [H]
    const int*  __restrict__ lenp,
    int T,
    float* __restrict__ EV)         // [NBN, T]
{
  const int bn  = blockIdx.y;
  const int len = lenp[bn];
  const int tid = threadIdx.x;
  const int wid = tid >> 6;
  const int t0  = blockIdx.x * 64 + wid * 16;   // this wave's 16-row tile
  if (t0 >= len) return;
  const int lane = tid & 63;
  const int li = lane & 15;       // A: row-in-tile / B: col(h)-in-tile
  const int kg = lane >> 4;       // k-octet selector

  const float* Xr = X + ((size_t)bn * T + t0 + li) * H + kg * 8;
  const short* Wr = Wt + li * H + kg * 8;

  f32x4 acc[16];
  const f32x4 zero = {0.f, 0.f, 0.f, 0.f};
#pragma unroll
  for (int ct = 0; ct < 16; ++ct) acc[ct] = zero;

#pragma unroll 2
  for (int k0 = 0; k0 < H; k0 += 32) {
    const float4 x0 = *(const float4*)(Xr + k0);
    const float4 x1 = *(const float4*)(Xr + k0 + 4);
    bf16x8 a;
    a[0] = f2b(x0.x); a[1] = f2b(x0.y); a[2] = f2b(x0.z); a[3] = f2b(x0.w);
    a[4] = f2b(x1.x); a[5] = f2b(x1.y); a[6] = f2b(x1.z); a[7] = f2b(x1.w);
    const short* wp = Wr + k0;
#pragma unroll
    for (int ct = 0; ct < 16; ++ct) {
      const bf16x8 b = *(const bf16x8*)(wp + ct * 16 * H);
      acc[ct] = __builtin_amdgcn_mfma_f32_16x16x32_bf16(a, b, acc[ct], 0, 0, 0);
    }
  }

  // epilogue: D[row=(lane>>4)*4+reg][col=lane&15]; tanh, *Vv, reduce over h
  float p0 = 0.f, p1 = 0.f, p2 = 0.f, p3 = 0.f;
#pragma unroll
  for (int ct = 0; ct < 16; ++ct) {
    const int hh = ct * 16 + li;
    const float u = U[bn * H + hh];
    const float v = Vv[hh];
    p0 = fmaf(tanh_fast(acc[ct][0] + u), v, p0);
    p1 = fmaf(tanh_fast(acc[ct][1] + u), v, p1);
    p2 = fmaf(tanh_fast(acc[ct][2] + u), v, p2);
    p3 = fmaf(tanh_fast(acc[ct][3] + u), v, p3);
  }
#pragma unroll
  for (int m = 1; m < 16; m <<= 1) {
    p0 += __shfl_xor(p0, m); p1 += __shfl_xor(p1, m);
    p2 += __shfl_xor(p2, m); p3 += __shfl_xor(p3, m);
  }
  if (li == 0) {
    float* e = EV + (size_t)bn * T + t0 + kg * 4;
    e[0] = p0; e[1] = p1; e[2] = p2; e[3] = p3;
  }
}

// ---------------------------------------------------------------------------
// K2a: per-bn softmax stats (max, 1/sum) over EV[0:len]; zero accumulator.
// ---------------------------------------------------------------------------
__global__ __launch_bounds__(256) void k_smax(
    const float* __restrict__ EV, const int* __restrict__ lenp,
    float* __restrict__ stats, float* __restrict__ ACC)
{
  const int bn = blockIdx.x, tid = threadIdx.x;
  const int len = lenp[bn];
  const float* ev = EV + (size_t)bn * TVV;
  __shared__ float red[8];

  float m = -1e30f;
  for (int t = tid; t < len; t += 256) m = fmaxf(m, ev[t]);
  for (int off = 32; off; off >>= 1) m = fmaxf(m, __shfl_xor(m, off));
  if ((tid & 63) == 0) red[tid >> 6] = m;
  __syncthreads();
  m = fmaxf(fmaxf(red[0], red[1]), fmaxf(red[2], red[3]));

  float s = 0.f;
  for (int t = tid; t < len; t += 256) s += __expf(ev[t] - m);
  for (int off = 32; off; off >>= 1) s += __shfl_xor(s, off);
  if ((tid & 63) == 0) red[4 + (tid >> 6)] = s;
  __syncthreads();
  if (tid == 0) {
    s = red[4] + red[5] + red[6] + red[7];
    stats[bn * 2]     = m;
    stats[bn * 2 + 1] = 1.f / s;
  }
  ACC[bn * H + tid] = 0.f;
}

// ---------------------------------------------------------------------------
// K2b: partial PV over a 256-row slab; atomicAdd into ACC.
// ---------------------------------------------------------------------------
__global__ __launch_bounds__(256) void k_pv(
    const float* __restrict__ EV, const float* __restrict__ X,
    const int* __restrict__ lenp, const float* __restrict__ stats,
    float* __restrict__ ACC)
{
  const int bn = blockIdx.y, tid = threadIdx.x;
  const int t0 = blockIdx.x * 256;
  const int len = lenp[bn];
  if (t0 >= len) return;
  const float m = stats[bn * 2], inv = stats[bn * 2 + 1];

  __shared__ float pl[256];
  const int t = t0 + tid;
  pl[tid] = (t < len) ? __expf(EV[(size_t)bn * TVV + t] - m) * inv : 0.f;
  __syncthreads();

  const int lim = min(256, len - t0);
  const float* Xb = X + ((size_t)bn * TVV + t0) * H;
  float acc = 0.f;
  int j = 0;
  for (; j + 8 <= lim; j += 8) {
#pragma unroll
    for (int u = 0; u < 8; ++u)
      acc = fmaf(pl[j + u], Xb[(size_t)(j + u) * H + tid], acc);
  }
  for (; j < lim; ++j) acc = fmaf(pl[j], Xb[(size_t)j * H + tid], acc);
  atomicAdd(&ACC[bn * H + tid], acc);
}

// ---------------------------------------------------------------------------
// K2-text: fused masked softmax + weighted sum (len <= 128, cheap).
// ---------------------------------------------------------------------------
template <int T>
__global__ __launch_bounds__(256) void k_softmax_pv(
    const float* __restrict__ EV, const float* __restrict__ X,
    const int* __restrict__ lenp, float* __restrict__ OUT)
{
  const int bn = blockIdx.x, tid = threadIdx.x;
  const int len = lenp[bn];
  __shared__ float pl[T];
  __shared__ float red[8];
  const float* ev = EV + (size_t)bn * T;

  float m = -1e30f;
  for (int t = tid; t < len; t += 256) m = fmaxf(m, ev[t]);
  for (int off = 32; off; off >>= 1) m = fmaxf(m, __shfl_xor(m, off));
  if ((tid & 63) == 0) red[tid >> 6] = m;
  __syncthreads();
  m = fmaxf(fmaxf(red[0], red[1]), fmaxf(red[2], red[3]));

  float s = 0.f;
  for (int t = tid; t < len; t += 256) {
    const float p = __expf(ev[t] - m);
    pl[t] = p;
    s += p;
  }
  for (int off = 32; off; off >>= 1) s += __shfl_xor(s, off);
  if ((tid & 63) == 0) red[4 + (tid >> 6)] = s;
  __syncthreads();
  s = red[4] + red[5] + red[6] + red[7];
  const float inv = 1.f / s;

  const float* Xb = X + (size_t)bn * T * H;
  float acc = 0.f;
  int t = 0;
  for (; t + 8 <= len; t += 8) {
#pragma unroll
    for (int j = 0; j < 8; ++j)
      acc = fmaf(pl[t + j], Xb[(size_t)(t + j) * H + tid], acc);
  }
  for (; t < len; ++t) acc = fmaf(pl[t], Xb[(size_t)t * H + tid], acc);
  OUT[bn * H + tid] = acc * inv;
}

// ---------------------------------------------------------------------------
// K3: final gating + output.
// ---------------------------------------------------------------------------
__global__ __launch_bounds__(256) void k_final(
    const float* __restrict__ HVS, const float* __restrict__ HTS,
    const float* __restrict__ Wvs, const float* __restrict__ bvs,
    const float* __restrict__ Wqs, const float* __restrict__ bqs,
    const float* __restrict__ Vbv, const float* __restrict__ Vbt,
    const float* __restrict__ bbv, const float* __restrict__ bbt,
    const float* __restrict__ wb,
    const float* __restrict__ WbsA, const float* __restrict__ HwhA,
    float* __restrict__ out)
{
  const int bn = blockIdx.x, tid = threadIdx.x;
  __shared__ float hv[H], ht[H];
  __shared__ float red[8];
  hv[tid] = HVS[bn * H + tid];
  ht[tid] = HTS[bn * H + tid];
  __syncthreads();

  const float wbs = WbsA[bn * H + tid];
  float hv2 = bvs[tid], ht2 = bqs[tid];
  float mv = bbv[tid] + wbs, mt = bbt[tid] + wbs;
#pragma unroll 4
  for (int k = 0; k < H; ++k) {
    const float a = hv[k], c = ht[k];
    hv2 = fmaf(a, Wvs[k * H + tid], hv2);
    ht2 = fmaf(c, Wqs[k * H + tid], ht2);
    mv  = fmaf(a, Vbv[k * H + tid], mv);
    mt  = fmaf(c, Vbt[k * H + tid], mt);
  }
  const float w = wb[tid];
  float sv = tanh_fast(mv) * w;
  float st = tanh_fast(mt) * w;
  for (int off = 32; off; off >>= 1) {
    sv += __shfl_xor(sv, off);
    st += __shfl_xor(st, off);
  }
  if ((tid & 63) == 0) { red[tid >> 6] = sv; red[4 + (tid >> 6)] = st; }
  __syncthreads();
  sv = red[0] + red[1] + red[2] + red[3];
  st = red[4] + red[5] + red[6] + red[7];
  const float mx = fmaxf(sv, st);
  const float e0 = __expf(sv - mx), e1 = __expf(st - mx);
  const float den = 1.f / (e0 + e1);
  out[bn * H + tid] = tanh_fast(HwhA[bn * H + tid] + (e0 * den) * hv2 + (e1 * den) * ht2);
}

// ---------------------------------------------------------------------------
extern "C" void kernel_launch(void* const* d_in, const int* in_sizes, int n_in,
                              void* d_out, int out_size, void* d_ws, size_t ws_size,
                              hipStream_t stream) {
  const float* h   = (const float*)d_in[0];
  const float* hf  = (const float*)d_in[1];
  const float* htx = (const float*)d_in[2];
  const float* Wav = (const float*)d_in[3];
  const float* Wat = (const float*)d_in[4];
  const float* Uav = (const float*)d_in[5];
  const float* Uat = (const float*)d_in[6];
  const float* Vav = (const float*)d_in[7];
  const float* Vat = (const float*)d_in[8];
  const float* bav = (const float*)d_in[9];
  const float* bat = (const float*)d_in[10];
  const float* Whh = (const float*)d_in[11];
  const float* bh  = (const float*)d_in[12];
  const float* Wvs = (const float*)d_in[13];
  const float* bvs = (const float*)d_in[14];
  const float* Wqs = (const float*)d_in[15];
  const float* bqs = (const float*)d_in[16];
  const float* Wb  = (const float*)d_in[17];
  const float* Vbv = (const float*)d_in[18];
  const float* Vbt = (const float*)d_in[19];
  const float* bbv = (const float*)d_in[20];
  const float* bbt = (const float*)d_in[21];
  const float* wb  = (const float*)d_in[22];
  const int* video_lens = (const int*)d_in[23];
  const int* qa_lens    = (const int*)d_in[24];

  float* ws    = (float*)d_ws;
  float* Uhv   = ws;                          // 160*256
  float* Uht   = Uhv  + NBN * H;
  float* WbsA  = Uht  + NBN * H;
  float* HwhA  = WbsA + NBN * H;
  float* HVS   = HwhA + NBN * H;
  float* HTS   = HVS  + NBN * H;
  float* EVb   = HTS  + NBN * H;              // 160*2048
  float* ETb   = EVb  + (size_t)NBN * TVV;    // 160*128
  float* stats = ETb  + (size_t)NBN * TQQ;    // 160*2
  int*   lenv  = (int*)(stats + NBN * 2);
  int*   lent  = lenv + NBN;
  short* Wtv   = (short*)(lent + NBN);        // 256*256 bf16 (16B-aligned)
  short* Wtt   = Wtv + H * H;

  k_wt<<<dim3(8, 8, 2), 256, 0, stream>>>(Wav, Wat, Wtv, Wtt);
  k_prep<<<NBN, 256, 0, stream>>>(h, Uav, Uat, Wb, Whh, bav, bat, bh,
                                  video_lens, qa_lens, Uhv, Uht, WbsA, HwhA,
                                  lenv, lent);
  k_logits_mfma<<<dim3(TVV / 64, NBN), 256, 0, stream>>>(hf, Wtv, Uhv, Vav, lenv, TVV, EVb);
  k_logits_mfma<<<dim3(TQQ / 64, NBN), 256, 0, stream>>>(htx, Wtt, Uht, Vat, lent, TQQ, ETb);
  k_smax<<<NBN, 256, 0, stream>>>(EVb, lenv, stats, HVS);
  k_pv<<<dim3(TVV / 256, NBN), 256, 0, stream>>>(EVb, hf, lenv, stats, HVS);
  k_softmax_pv<TQQ><<<NBN, 256, 0, stream>>>(ETb, htx, lent, HTS);
  k_final<<<NBN, 256, 0, stream>>>(HVS, HTS, Wvs, bvs, Wqs, bqs, Vbv, Vbt,
                                   bbv, bbt, wb, WbsA, HwhA, (float*)d_out);
}